// Round 9
// baseline (244.375 us; speedup 1.0000x reference)
//
#include <hip/hip_runtime.h>

// LoG: GaussianBlur(3x3, sigma=1, BORDER_REFLECT_101) -> Laplacian(ksize=9) -> +1 -> clip[0,255]
// x: [32,512,512,3] float32 NHWC. out: same.
//
// Factorization: S9 = C6*[1,2,1], D9 = C6*[1,-2,1], C6 = {1,6,15,20,15,6,1}
//   lap = outer(S9,D9)+outer(D9,S9) = (C6 (x) C6) o [[2,0,2],[0,-8,0],[2,0,2]]
// Pipeline (3 barriers), per 32x32 tile:
//   s1: horiz G3, global -> hblur (42 rows x 120 fl), depth-1 load prefetch
//   fv: vert 9-tap U9 = G3v*C6v, hblur -> vq (34 x 124), 3-row register blocks
//   3b: horiz 7-tap C6, vq -> P (34 x 108), 8 outputs/lane
//   3c: 5-point cross on P -> +1, clip, store
//
// R9 rationale (R1-R8 evidence): five structurally different kernels all sat
// at 107-111us while VALU work varied 1.5x and LDS ops 2x -> not pipe-bound;
// block-LATENCY-bound at ~4 resident blocks/CU. So: TH 16->32 (half the
// blocks/barriers per output, halo redundancy 1.625->1.31), s1 prefetch to
// break its serial load->compute->ds_write chain, vectorized edge-col s1.
// SQ_LDS_BANK_CONFLICT proven non-causal (R8: ops halved, counter rose).

#define TH 32
#define TW 32
#define BF 120           // hblur row: 40 px = 120 floats (+-4 px halo)
#define PH (TH+2)        // 34 vq/P rows (out rows -1..32)
#define VW 124           // vq row stride (30 data quads + 1 zeroed pad quad)
#define PW 108           // P row stride (26 quads written)
#define HIMG 512
#define WIMG 512
#define ROWF (WIMG*3)    // 1536 floats per image row

// LDS floats: hblur [0,5040) (42x120); vq [5040,9256) (34x124);
//             P [0,3672) aliases hblur (dead after fv).
#define OFF_VQ 5040
#define SM_TOTAL 9256    // 37024 B -> 4 blocks/CU

__device__ __forceinline__ int reflect101(int i, int n) {
    i = (i < 0) ? -i : i;
    return (i >= n) ? (2 * n - 2 - i) : i;
}

__device__ __forceinline__ float4 fma4(float s, const float4& a, const float4& b) {
    return make_float4(fmaf(s, a.x, b.x), fmaf(s, a.y, b.y),
                       fmaf(s, a.z, b.z), fmaf(s, a.w, b.w));
}

__device__ __forceinline__ float c6dot(float f0, float f1, float f2, float f3,
                                       float f4, float f5, float f6) {
    return fmaf(20.f, f3, fmaf(6.f, f1 + f5, fmaf(15.f, f2 + f4, f0 + f6)));
}

// U9 = conv(G3, C6), symmetric 9-tap, sum 64
#define U0 0.27406862f
#define U1 2.09627447f
#define U2 7.09627447f
#define U3 13.90372553f
#define U4 17.25931382f

__global__ __launch_bounds__(256, 4)
void log_fused(const float* __restrict__ x, float* __restrict__ out) {
    __shared__ __align__(16) float smem[SM_TOTAL];
    float* const hblur = smem;            // 42 x 120
    float* const P     = smem;            // 34 x 108 (aliases hblur after fv)
    float* const vq    = smem + OFF_VQ;   // 34 x 124

    const int tid  = threadIdx.x;
    const int col0 = blockIdx.x * TW;
    const int row0 = blockIdx.y * TH;
    const int n    = blockIdx.z;
    const float* const xi = x + (size_t)n * HIMG * ROWF;

    const int R0    = max(0, row0 - 5);
    const int R1    = min(HIMG - 1, row0 + TH + 4);
    const int nrows = R1 - R0 + 1;   // 42 interior, 37 at row boundaries

    const float G0 = 0.2740686190f, G1 = 0.4518627620f;  // normalized exp(-{1,0,1}/2)

    // Zero vq pad quads (floats 120..123): 3b's qp=12 window reads up to float
    // 123; no LDS read may touch uninitialized words (R4 lesson).
    if (tid < PH)
        *(float4*)&vq[tid * VW + 120] = make_float4(0.f, 0.f, 0.f, 0.f);

    // ---- s1: horizontal 3-tap Gaussian, global -> hblur ----
    const bool edgecol = (col0 == 0) || (col0 + TW == WIMG);
    if (!edgecol) {
        // Column-stationary, depth-1 prefetch: next row's 3 loads issue before
        // the current row's compute, breaking the serial chain.
        if (tid < 240) {
            const int cg = tid % 30;
            const int rg = tid / 30;            // 0..7
            const float* xp = xi + (size_t)(R0 + rg) * ROWF
                                 + (3 * (col0 - 4) + 4 * cg - 4);
            float* hb = hblur + rg * BF + 4 * cg;
            int r = rg;
            float4 A0 = *(const float4*)(xp);
            float4 A1 = *(const float4*)(xp + 4);
            float4 A2 = *(const float4*)(xp + 8);
            while (true) {
                const int rn = r + 8;
                const bool hn = rn < nrows;
                const float* xn = xp + 8 * ROWF;
                float4 B0, B1, B2;
                if (hn) {
                    B0 = *(const float4*)(xn);
                    B1 = *(const float4*)(xn + 4);
                    B2 = *(const float4*)(xn + 8);
                }
                float4 o;
                o.x = G0 * (A0.y + A1.w) + G1 * A1.x;
                o.y = G0 * (A0.z + A2.x) + G1 * A1.y;
                o.z = G0 * (A0.w + A2.y) + G1 * A1.z;
                o.w = G0 * (A1.x + A2.z) + G1 * A1.w;
                *(float4*)hb = o;
                if (!hn) break;
                A0 = B0; A1 = B1; A2 = B2;
                r = rn; xp = xn; hb += 8 * BF;
            }
        }
    } else {
        // Edge-column blocks (2/16): vectorized per-quad with scalar fallback
        // only for reflected quads (~4-5 of 30). Kills the old 39-serial-load
        // straggler path.
        for (int e = tid; e < nrows * 30; e += 256) {
            const int row = e / 30;
            const int q   = e - row * 30;
            const float* xr = xi + (size_t)(R0 + row) * ROWF;
            const int lcpmin = (4 * q) / 3;
            const int lcpmax = (4 * q + 3) / 3;
            const bool safe = (col0 - 5 + lcpmin >= 0) && (col0 - 3 + lcpmax <= WIMG - 1);
            float4 o;
            if (safe) {
                const float* p = xr + (3 * col0 - 16 + 4 * q);   // 16B aligned
                const float4 a = *(const float4*)(p);
                const float4 b = *(const float4*)(p + 4);
                const float4 c = *(const float4*)(p + 8);
                o.x = G0 * (a.y + b.w) + G1 * b.x;
                o.y = G0 * (a.z + c.x) + G1 * b.y;
                o.z = G0 * (a.w + c.y) + G1 * b.z;
                o.w = G0 * (b.x + c.z) + G1 * b.w;
            } else {
                float t[4];
                #pragma unroll
                for (int m = 0; m < 4; ++m) {
                    const int lc  = 4 * q + m;
                    const int lcp = lc / 3;
                    const int ch  = lc - 3 * lcp;
                    const int gc  = reflect101(col0 - 4 + lcp, WIMG);
                    const int xm  = reflect101(gc - 1, WIMG) * 3 + ch;
                    const int x0  = gc * 3 + ch;
                    const int xp2 = reflect101(gc + 1, WIMG) * 3 + ch;
                    t[m] = G0 * (xr[xm] + xr[xp2]) + G1 * xr[x0];
                }
                o = make_float4(t[0], t[1], t[2], t[3]);
            }
            *(float4*)&hblur[row * BF + 4 * q] = o;
        }
    }
    __syncthreads();

    // ---- fv: fused vertical 9-tap (G3v * C6v), hblur -> vq ----
    if (row0 != 0 && row0 != HIMG - TH) {
        // Interior row-tiles: vq[r] = sum_j U9[j]*hblur[r+j] (no reflect:
        // hblur row h <-> image row row0-5+h, all in [0,511]). 3-row register
        // blocks; last triple starts at row 31 (rows 31,32 double-written with
        // identical values by tg=10/11 -- benign).
        const float U9k[9] = {U0, U1, U2, U3, U4, U3, U2, U1, U0};
        for (int g = tid; g < 360; g += 256) {   // 12 triples x 30 quads
            const int tg = g / 30;
            const int qc = g - tg * 30;
            const int s  = min(3 * tg, PH - 3);  // 0,3,..,30,31
            const float* hb = hblur + s * BF + 4 * qc;
            float4 a0 = make_float4(0.f, 0.f, 0.f, 0.f), a1 = a0, a2 = a0;
            #pragma unroll
            for (int j = 0; j < 11; ++j) {
                const float4 w = *(const float4*)(hb + j * BF);
                if (j <= 8)           a0 = fma4(U9k[j],     w, a0);
                if (j >= 1 && j <= 9) a1 = fma4(U9k[j - 1], w, a1);
                if (j >= 2)           a2 = fma4(U9k[j - 2], w, a2);
            }
            float* vp = vq + s * VW + 4 * qc;
            *(float4*)vp            = a0;
            *(float4*)(vp + VW)     = a1;
            *(float4*)(vp + 2 * VW) = a2;
        }
    } else {
        // Boundary row-tiles (2/16): exact per-stage double-reflect.
        // vq[r] = sum_k C6[k]*blur_img[reflect(row0-4+r+k)], blur_img[y] =
        // G0*(hbI[refl(y-1)]+hbI[refl(y+1)]) + G1*hbI[y], hbI[y] at hblur[y-R0].
        const float C6k[7] = {1.f, 6.f, 15.f, 20.f, 15.f, 6.f, 1.f};
        for (int g = tid; g < PH * 30; g += 256) {   // 1020 groups
            const int r  = g / 30;
            const int qc = g - r * 30;
            const int gb = row0 - 4 + r;
            float4 acc = make_float4(0.f, 0.f, 0.f, 0.f);
            #pragma unroll
            for (int k = 0; k < 7; ++k) {
                const int y  = reflect101(gb + k, HIMG);
                const int ym = reflect101(y - 1, HIMG) - R0;
                const int yp = reflect101(y + 1, HIMG) - R0;
                const float4 a = *(const float4*)&hblur[ym * BF + 4 * qc];
                const float4 b = *(const float4*)&hblur[(y - R0) * BF + 4 * qc];
                const float4 c = *(const float4*)&hblur[yp * BF + 4 * qc];
                const float4 gg = make_float4(G0 * (a.x + c.x) + G1 * b.x,
                                              G0 * (a.y + c.y) + G1 * b.y,
                                              G0 * (a.z + c.z) + G1 * b.z,
                                              G0 * (a.w + c.w) + G1 * b.w);
                acc = fma4(C6k[k], gg, acc);
            }
            *(float4*)&vq[r * VW + 4 * qc] = acc;
        }
    }
    __syncthreads();   // hblur dead beyond this point (P overlays it)

    // ---- 3b: horizontal 7-tap C6, vq -> P (8 outputs/lane) ----
    // P[r][ps] = sum_k C6[k]*vq[r][ps+3k]; window floats 8qp..8qp+27 (7 f4
    // reads; qp=12's last read touches the zeroed pad).
    for (int g = tid; g < PH * 13; g += 256) {   // 442 groups
        const int r  = g / 13;
        const int qp = g - r * 13;
        const float* v = vq + r * VW + 8 * qp;
        float f[28];
        #pragma unroll
        for (int c = 0; c < 7; ++c) {
            const float4 w = *(const float4*)(v + 4 * c);
            f[4*c+0] = w.x; f[4*c+1] = w.y; f[4*c+2] = w.z; f[4*c+3] = w.w;
        }
        float p[8];
        #pragma unroll
        for (int j = 0; j < 8; ++j)
            p[j] = c6dot(f[j], f[j+3], f[j+6], f[j+9], f[j+12], f[j+15], f[j+18]);
        float* pr = P + r * PW + 8 * qp;
        *(float4*)pr       = make_float4(p[0], p[1], p[2], p[3]);
        *(float4*)(pr + 4) = make_float4(p[4], p[5], p[6], p[7]);
    }
    __syncthreads();

    // ---- 3c: 5-point cross on P, +1, clip, store (8 outputs/lane) ----
    // out[i][c] = 2*(P[i][c]+P[i][c+6]+P[i+2][c]+P[i+2][c+6]) - 8*P[i+1][c+3] + 1
    float* const outn = out + (size_t)n * HIMG * ROWF;
    for (int g = tid; g < TH * 12; g += 256) {   // 384 groups
        const int i  = g / 12;
        const int qp = g - i * 12;
        const int o  = qp * 8;
        const float* pt = P + i * PW + o;
        const float* pm = pt + PW;
        const float* pb = pm + PW;
        float t[16], m[12], b[16];
        #pragma unroll
        for (int q = 0; q < 4; ++q) {
            const float4 vt = *(const float4*)(pt + 4 * q);
            t[4*q+0] = vt.x; t[4*q+1] = vt.y; t[4*q+2] = vt.z; t[4*q+3] = vt.w;
            const float4 vb = *(const float4*)(pb + 4 * q);
            b[4*q+0] = vb.x; b[4*q+1] = vb.y; b[4*q+2] = vb.z; b[4*q+3] = vb.w;
        }
        #pragma unroll
        for (int q = 0; q < 3; ++q) {          // only m[3..10] consumed
            const float4 vm = *(const float4*)(pm + 4 * q);
            m[4*q+0] = vm.x; m[4*q+1] = vm.y; m[4*q+2] = vm.z; m[4*q+3] = vm.w;
        }
        float o8[8];
        #pragma unroll
        for (int j = 0; j < 8; ++j) {
            const float c = m[j + 3];
            const float s = (t[j] - c) + (t[j + 6] - c) + (b[j] - c) + (b[j + 6] - c);
            const float v = fmaf(2.f, s, 1.f);
            o8[j] = fminf(fmaxf(v, 0.f), 255.f);
        }
        float* op = outn + (size_t)(row0 + i) * ROWF + (size_t)(col0 * 3 + o);
        *(float4*)op       = make_float4(o8[0], o8[1], o8[2], o8[3]);
        *(float4*)(op + 4) = make_float4(o8[4], o8[5], o8[6], o8[7]);
    }
}

extern "C" void kernel_launch(void* const* d_in, const int* in_sizes, int n_in,
                              void* d_out, int out_size, void* d_ws, size_t ws_size,
                              hipStream_t stream) {
    const float* x = (const float*)d_in[0];
    float* outp = (float*)d_out;
    const int nimg = in_sizes[0] / (HIMG * WIMG * 3);
    dim3 grid(WIMG / TW, HIMG / TH, nimg);
    log_fused<<<grid, dim3(256, 1, 1), 0, stream>>>(x, outp);
}

// Round 10
// 232.949 us; speedup vs baseline: 1.0491x; 1.0491x over previous
//
#include <hip/hip_runtime.h>

// LoG: GaussianBlur(3x3, sigma=1, BORDER_REFLECT_101) -> Laplacian(ksize=9) -> +1 -> clip[0,255]
// x: [32,512,512,3] float32 NHWC. out: same.
//
// Factorization: S9 = C6*[1,2,1], D9 = C6*[1,-2,1], C6 = {1,6,15,20,15,6,1}
//   lap = outer(S9,D9)+outer(D9,S9) = (C6 (x) C6) o [[2,0,2],[0,-8,0],[2,0,2]]
// Pipeline (3 barriers), per 32x16 tile:  [R8 structure, proven 108us]
//   s1: horiz G3, global -> hblur (26x120)   ** R10: fully load-hoisted **
//   fv: vert 9-tap U9 = G3v*C6v, hblur -> vq (18x124), single-shot 180 thr
//   3b: horiz 7-tap C6, vq -> P (18x108), single-shot 234 thr
//   3c: 5-pt cross on P -> +1, clip, store, single-shot 192 thr
//
// R10 rationale: R1-R9 established time ~ block_latency / resident_blocks
// (work changes are invisible; occupancy changes are not). The only
// multi-iteration stage is s1 (3-4 serial {3 gloads -> compute -> ds_write}
// rounds = ~2.5-3k cyc of the ~5k block critical path). This round unrolls s1
// into explicit phases with ALL 12 loads issued before any compute, removing
// the dependent-load chain. launch_bounds(256,5) (VGPR cap 102) avoids the
// R3/R4 spill cliff while keeping >=5 waves/SIMD possible.
// SQ_LDS_BANK_CONFLICT proven non-causal (R8: ops -25%, counter +12%, flat).

#define TH 16
#define TW 32
#define BF 120           // hblur row: 40 px = 120 floats (+-4 px halo)
#define PH (TH+2)        // 18 vq/P rows (out rows -1..16)
#define VW 124           // vq row stride (30 data quads + 1 zeroed pad quad)
#define PW 108           // P row stride (26 quads written)
#define HIMG 512
#define WIMG 512
#define ROWF (WIMG*3)    // 1536 floats per image row

// LDS floats: hblur [0,3120) (26x120); vq [3120,5352) (18x124);
//             P [0,1944) aliases hblur (dead after fv).
#define OFF_VQ 3120
#define SM_TOTAL 5352    // 21408 B -> 7 blocks/CU

__device__ __forceinline__ int reflect101(int i, int n) {
    i = (i < 0) ? -i : i;
    return (i >= n) ? (2 * n - 2 - i) : i;
}

__device__ __forceinline__ float4 fma4(float s, const float4& a, const float4& b) {
    return make_float4(fmaf(s, a.x, b.x), fmaf(s, a.y, b.y),
                       fmaf(s, a.z, b.z), fmaf(s, a.w, b.w));
}

__device__ __forceinline__ float c6dot(float f0, float f1, float f2, float f3,
                                       float f4, float f5, float f6) {
    return fmaf(20.f, f3, fmaf(6.f, f1 + f5, fmaf(15.f, f2 + f4, f0 + f6)));
}

// horizontal 3-tap G3 on a 12-float window {a,b,c} -> 4 outputs
__device__ __forceinline__ float4 hg3(const float4& a, const float4& b, const float4& c,
                                      float G0, float G1) {
    return make_float4(G0 * (a.y + b.w) + G1 * b.x,
                       G0 * (a.z + c.x) + G1 * b.y,
                       G0 * (a.w + c.y) + G1 * b.z,
                       G0 * (b.x + c.z) + G1 * b.w);
}

// U9 = conv(G3, C6), symmetric 9-tap, sum 64
#define U0 0.27406862f
#define U1 2.09627447f
#define U2 7.09627447f
#define U3 13.90372553f
#define U4 17.25931382f

__global__ __launch_bounds__(256, 5)
void log_fused(const float* __restrict__ x, float* __restrict__ out) {
    __shared__ __align__(16) float smem[SM_TOTAL];
    float* const hblur = smem;            // 26 x 120
    float* const P     = smem;            // 18 x 108 (aliases hblur after fv)
    float* const vq    = smem + OFF_VQ;   // 18 x 124

    const int tid  = threadIdx.x;
    const int col0 = blockIdx.x * TW;
    const int row0 = blockIdx.y * TH;
    const int n    = blockIdx.z;
    const float* const xi = x + (size_t)n * HIMG * ROWF;

    const int R0    = max(0, row0 - 5);
    const int R1    = min(HIMG - 1, row0 + TH + 4);
    const int nrows = R1 - R0 + 1;   // 26 interior, 21 at row boundaries

    const float G0 = 0.2740686190f, G1 = 0.4518627620f;  // normalized exp(-{1,0,1}/2)

    // Zero vq pad quads (floats 120..123): 3b's qp=12 window reads up to float
    // 123; no LDS read may touch uninitialized words (R4 lesson).
    if (tid < PH)
        *(float4*)&vq[tid * VW + 120] = make_float4(0.f, 0.f, 0.f, 0.f);

    // ---- s1: horizontal 3-tap Gaussian, global -> hblur ----
    const bool edgecol = (col0 == 0) || (col0 + TW == WIMG);
    if (!edgecol) {
        // Column-stationary; rows rg, rg+8, rg+16 (always: nrows>=21), rg+24
        // (interior only, rg<2). ALL loads issued before any compute: no
        // dependent-load chain. 12 f4 in flight = 48 VGPR.
        if (tid < 240) {
            const int cg = tid % 30;
            const int rg = tid / 30;            // 0..7
            const float* xb = xi + (size_t)(R0 + rg) * ROWF
                                 + (3 * (col0 - 4) + 4 * cg - 4);
            float* hb = hblur + rg * BF + 4 * cg;
            const bool h2 = rg + 16 < nrows;
            const bool h3 = rg + 24 < nrows;
            const float* x1 = xb + (size_t)8  * ROWF;
            const float* x2 = xb + (size_t)16 * ROWF;
            const float* x3 = xb + (size_t)24 * ROWF;
            const float4 a0 = *(const float4*)(xb);
            const float4 a1 = *(const float4*)(xb + 4);
            const float4 a2 = *(const float4*)(xb + 8);
            const float4 b0 = *(const float4*)(x1);
            const float4 b1 = *(const float4*)(x1 + 4);
            const float4 b2 = *(const float4*)(x1 + 8);
            float4 c0, c1, c2, d0, d1, d2;
            if (h2) {
                c0 = *(const float4*)(x2);
                c1 = *(const float4*)(x2 + 4);
                c2 = *(const float4*)(x2 + 8);
            }
            if (h3) {
                d0 = *(const float4*)(x3);
                d1 = *(const float4*)(x3 + 4);
                d2 = *(const float4*)(x3 + 8);
            }
            *(float4*)hb = hg3(a0, a1, a2, G0, G1);
            *(float4*)(hb + 8 * BF) = hg3(b0, b1, b2, G0, G1);
            if (h2) *(float4*)(hb + 16 * BF) = hg3(c0, c1, c2, G0, G1);
            if (h3) *(float4*)(hb + 24 * BF) = hg3(d0, d1, d2, G0, G1);
        }
    } else {
        // Edge-column blocks (2/16): vectorized per-quad, scalar fallback only
        // for reflected quads.
        for (int e = tid; e < nrows * 30; e += 256) {
            const int row = e / 30;
            const int q   = e - row * 30;
            const float* xr = xi + (size_t)(R0 + row) * ROWF;
            const int lcpmin = (4 * q) / 3;
            const int lcpmax = (4 * q + 3) / 3;
            const bool safe = (col0 - 5 + lcpmin >= 0) && (col0 - 3 + lcpmax <= WIMG - 1);
            float4 o;
            if (safe) {
                const float* p = xr + (3 * col0 - 16 + 4 * q);   // 16B aligned
                const float4 a = *(const float4*)(p);
                const float4 b = *(const float4*)(p + 4);
                const float4 c = *(const float4*)(p + 8);
                o = hg3(a, b, c, G0, G1);
            } else {
                float t[4];
                #pragma unroll
                for (int m = 0; m < 4; ++m) {
                    const int lc  = 4 * q + m;
                    const int lcp = lc / 3;
                    const int ch  = lc - 3 * lcp;
                    const int gc  = reflect101(col0 - 4 + lcp, WIMG);
                    const int xm  = reflect101(gc - 1, WIMG) * 3 + ch;
                    const int x0  = gc * 3 + ch;
                    const int xp2 = reflect101(gc + 1, WIMG) * 3 + ch;
                    t[m] = G0 * (xr[xm] + xr[xp2]) + G1 * xr[x0];
                }
                o = make_float4(t[0], t[1], t[2], t[3]);
            }
            *(float4*)&hblur[row * BF + 4 * q] = o;
        }
    }
    __syncthreads();

    // ---- fv: fused vertical 9-tap (G3v * C6v), hblur -> vq ----
    if (row0 != 0 && row0 != HIMG - TH) {
        // Interior row-tiles: vq[r] = sum_j U9[j]*hblur[r+j] (no reflect:
        // hblur row h <-> image row row0-5+h, all in [0,511]).
        if (tid < 180) {                       // 6 row-triples x 30 quads
            const int rg = tid / 30;           // 0..5
            const int qc = tid % 30;
            const float U9k[9] = {U0, U1, U2, U3, U4, U3, U2, U1, U0};
            const float* hb = hblur + (3 * rg) * BF + 4 * qc;
            float4 a0 = make_float4(0.f, 0.f, 0.f, 0.f), a1 = a0, a2 = a0;
            #pragma unroll
            for (int j = 0; j < 11; ++j) {
                const float4 w = *(const float4*)(hb + j * BF);
                if (j <= 8)           a0 = fma4(U9k[j],     w, a0);
                if (j >= 1 && j <= 9) a1 = fma4(U9k[j - 1], w, a1);
                if (j >= 2)           a2 = fma4(U9k[j - 2], w, a2);
            }
            float* vp = vq + (3 * rg) * VW + 4 * qc;
            *(float4*)vp            = a0;
            *(float4*)(vp + VW)     = a1;
            *(float4*)(vp + 2 * VW) = a2;
        }
    } else {
        // Boundary row-tiles (2/32): exact per-stage double-reflect.
        // vq[r] = sum_k C6[k]*blur_img[reflect(row0-4+r+k)], blur_img[y] =
        // G0*(hbI[refl(y-1)]+hbI[refl(y+1)]) + G1*hbI[y], hbI[y] at hblur[y-R0].
        const float C6k[7] = {1.f, 6.f, 15.f, 20.f, 15.f, 6.f, 1.f};
        for (int g = tid; g < PH * 30; g += 256) {   // 540 groups
            const int r  = g / 30;
            const int qc = g - r * 30;
            const int gb = row0 - 4 + r;
            float4 acc = make_float4(0.f, 0.f, 0.f, 0.f);
            #pragma unroll
            for (int k = 0; k < 7; ++k) {
                const int y  = reflect101(gb + k, HIMG);
                const int ym = reflect101(y - 1, HIMG) - R0;
                const int yp = reflect101(y + 1, HIMG) - R0;
                const float4 a = *(const float4*)&hblur[ym * BF + 4 * qc];
                const float4 b = *(const float4*)&hblur[(y - R0) * BF + 4 * qc];
                const float4 c = *(const float4*)&hblur[yp * BF + 4 * qc];
                const float4 gg = make_float4(G0 * (a.x + c.x) + G1 * b.x,
                                              G0 * (a.y + c.y) + G1 * b.y,
                                              G0 * (a.z + c.z) + G1 * b.z,
                                              G0 * (a.w + c.w) + G1 * b.w);
                acc = fma4(C6k[k], gg, acc);
            }
            *(float4*)&vq[r * VW + 4 * qc] = acc;
        }
    }
    __syncthreads();   // hblur dead beyond this point (P overlays it)

    // ---- 3b: horizontal 7-tap C6, vq -> P (8 outputs/lane, single shot) ----
    // P[r][ps] = sum_k C6[k]*vq[r][ps+3k]; window floats 8qp..8qp+27 (7 f4
    // reads; qp=12's last read touches the zeroed pad).
    if (tid < PH * 13) {                        // 234 threads
        const int qp = tid % 13;
        const int r  = tid / 13;
        const float* v = vq + r * VW + 8 * qp;
        float f[28];
        #pragma unroll
        for (int c = 0; c < 7; ++c) {
            const float4 w = *(const float4*)(v + 4 * c);
            f[4*c+0] = w.x; f[4*c+1] = w.y; f[4*c+2] = w.z; f[4*c+3] = w.w;
        }
        float p[8];
        #pragma unroll
        for (int j = 0; j < 8; ++j)
            p[j] = c6dot(f[j], f[j+3], f[j+6], f[j+9], f[j+12], f[j+15], f[j+18]);
        float* pr = P + r * PW + 8 * qp;
        *(float4*)pr       = make_float4(p[0], p[1], p[2], p[3]);
        *(float4*)(pr + 4) = make_float4(p[4], p[5], p[6], p[7]);
    }
    __syncthreads();

    // ---- 3c: 5-point cross on P, +1, clip, store (8 outputs/lane) ----
    // out[i][c] = 2*(P[i][c]+P[i][c+6]+P[i+2][c]+P[i+2][c+6]) - 8*P[i+1][c+3] + 1
    float* const outn = out + (size_t)n * HIMG * ROWF;
    if (tid < TH * 12) {                        // 192 threads
        const int qp = tid % 12;
        const int i  = tid / 12;
        const int o  = qp * 8;
        const float* pt = P + i * PW + o;
        const float* pm = pt + PW;
        const float* pb = pm + PW;
        float t[16], m[12], b[16];
        #pragma unroll
        for (int q = 0; q < 4; ++q) {
            const float4 vt = *(const float4*)(pt + 4 * q);
            t[4*q+0] = vt.x; t[4*q+1] = vt.y; t[4*q+2] = vt.z; t[4*q+3] = vt.w;
            const float4 vb = *(const float4*)(pb + 4 * q);
            b[4*q+0] = vb.x; b[4*q+1] = vb.y; b[4*q+2] = vb.z; b[4*q+3] = vb.w;
        }
        #pragma unroll
        for (int q = 0; q < 3; ++q) {          // only m[3..10] consumed
            const float4 vm = *(const float4*)(pm + 4 * q);
            m[4*q+0] = vm.x; m[4*q+1] = vm.y; m[4*q+2] = vm.z; m[4*q+3] = vm.w;
        }
        float o8[8];
        #pragma unroll
        for (int j = 0; j < 8; ++j) {
            const float c = m[j + 3];
            const float s = (t[j] - c) + (t[j + 6] - c) + (b[j] - c) + (b[j + 6] - c);
            const float v = fmaf(2.f, s, 1.f);
            o8[j] = fminf(fmaxf(v, 0.f), 255.f);
        }
        float* op = outn + (size_t)(row0 + i) * ROWF + (size_t)(col0 * 3 + o);
        *(float4*)op       = make_float4(o8[0], o8[1], o8[2], o8[3]);
        *(float4*)(op + 4) = make_float4(o8[4], o8[5], o8[6], o8[7]);
    }
}

extern "C" void kernel_launch(void* const* d_in, const int* in_sizes, int n_in,
                              void* d_out, int out_size, void* d_ws, size_t ws_size,
                              hipStream_t stream) {
    const float* x = (const float*)d_in[0];
    float* outp = (float*)d_out;
    const int nimg = in_sizes[0] / (HIMG * WIMG * 3);
    dim3 grid(WIMG / TW, HIMG / TH, nimg);
    log_fused<<<grid, dim3(256, 1, 1), 0, stream>>>(x, outp);
}